// Round 8
// baseline (371.324 us; speedup 1.0000x reference)
//
#include <hip/hip_runtime.h>

// Adaptive softmax NLL — barrier-free bf16-MFMA GEMM: both operands pre-packed
// into MFMA fragment order; K-loop is pure global-load + MFMA (no LDS, no syncs).
//
// Packed tile layout (128 rows x 512 k = 128KB): frag16 index e = ke*128 + row,
// ke = kt*8 + ks*4 + kg  (k0 = kt*64 + ks*32 + kg*8); each frag = 8 bf16 (16B).
// Weight: 396 chunk-tiles (head 0..39, t1 40..118, t2 119..236, t3 237..395),
// padded rows w=0 / bias=-1e30 (vanish in exp-weighted LSE merges).
// Hidden: 32 tiles natural order + 37 tiles bucketed-compacted (128-padded).

#define D 512
#define NROWS_PAD 50688
#define NTOK 4096
#define NTOKP 4736
#define HEAD_CHUNKS 40
#define TAILP_STRIDE 160
#define HP_TILES 32
#define WFRAG_BLOCKS 25344   // 396 chunks * 64 ke

typedef __attribute__((ext_vector_type(8))) short short8;
typedef __attribute__((ext_vector_type(4))) float f32x4;

__device__ __forceinline__ unsigned short f2bf(float f) {
    unsigned int u = __float_as_uint(f);
    u += 0x7FFFu + ((u >> 16) & 1u);
    return (unsigned short)(u >> 16);
}

// ---------------- bucket tokens by cluster (deterministic counting sort) ----------------
__global__ __launch_bounds__(256) void k_bucket(
    const int* __restrict__ target, int* __restrict__ perm,
    int* __restrict__ inv, int* __restrict__ meta)
{
    __shared__ int cnt[256][4];
    __shared__ int basesh[256][4];
    __shared__ int sTot[4], sOff[4];
    const int th = threadIdx.x;
    for (int p = th; p < NTOKP; p += 256) perm[p] = -1;
    int lc[4] = {0, 0, 0, 0};
    #pragma unroll
    for (int i = 0; i < 16; ++i) {
        int tg = target[th * 16 + i];
        int c = (tg >= 5000) + (tg >= 15000) + (tg >= 30000);
        lc[c]++;
    }
    #pragma unroll
    for (int c = 0; c < 4; ++c) cnt[th][c] = lc[c];
    __syncthreads();
    if (th < 4) {
        int tot = 0;
        for (int i = 0; i < 256; ++i) tot += cnt[i][th];
        sTot[th] = tot;
    }
    __syncthreads();
    if (th == 0) {
        int b = 0;
        for (int c = 1; c < 4; ++c) { sOff[c] = b; b += ((sTot[c] + 127) >> 7) << 7; }
        meta[0] = sTot[1]; meta[1] = sTot[2]; meta[2] = sTot[3];
        meta[3] = sOff[1]; meta[4] = sOff[2]; meta[5] = sOff[3];
        meta[6] = (sTot[1] + 127) >> 7;
        meta[7] = (sTot[2] + 127) >> 7;
        meta[8] = (sTot[3] + 127) >> 7;
    }
    __syncthreads();
    if (th >= 1 && th < 4) {
        int run = sOff[th];
        for (int i = 0; i < 256; ++i) { basesh[i][th] = run; run += cnt[i][th]; }
    }
    __syncthreads();
    int run[4];
    #pragma unroll
    for (int c = 1; c < 4; ++c) run[c] = basesh[th][c];
    for (int i = 0; i < 16; ++i) {
        int t = th * 16 + i;
        int tg = target[t];
        int c = (tg >= 5000) + (tg >= 15000) + (tg >= 30000);
        if (c > 0) { int pos = run[c]++; perm[pos] = t; inv[t] = pos; }
        else inv[t] = -1;
    }
}

// ---------------- convert: pack weight + hidden into fragment order ----------------
__global__ __launch_bounds__(128) void k_convert(
    const float* __restrict__ weight, const float* __restrict__ bias,
    const float* __restrict__ cweight, const float* __restrict__ cbias,
    const float* __restrict__ hidden, const int* __restrict__ perm,
    unsigned short* __restrict__ Wp, float* __restrict__ wsB,
    unsigned short* __restrict__ Hp, unsigned short* __restrict__ Hcp)
{
    const int b = blockIdx.x;
    const int i = threadIdx.x;   // 0..127
    if (b < WFRAG_BLOCKS) {
        // weight packing: block = (chunk, ke); thread = row-in-chunk
        const int chunk = b >> 6, ke = b & 63;
        const int R = chunk * 128 + i;          // padded row id
        const int pstart[4] = {0, 5120, 15232, 30336};
        const int plen[4]   = {5003, 10000, 15000, 20257};
        const int psrc[4]   = {0, 5000, 15000, 30000};
        int p = (R < 5120) ? 0 : (R < 15232) ? 1 : (R < 30336) ? 2 : 3;
        int o = R - pstart[p];
        const float* src = nullptr;
        float bval = -1e30f;
        if (o < plen[p]) {
            if (p == 0 && o >= 5000) { src = cweight + (size_t)(o - 5000) * D; bval = cbias[o - 5000]; }
            else { int sr = psrc[p] + o; src = weight + (size_t)sr * D; bval = bias[sr]; }
        }
        const int k0 = (ke >> 3) * 64 + ((ke >> 2) & 1) * 32 + (ke & 3) * 8;
        ushort4 u0 = {0, 0, 0, 0}, u1 = {0, 0, 0, 0};
        if (src) {
            float4 a = *(const float4*)(src + k0);
            float4 c = *(const float4*)(src + k0 + 4);
            u0.x = f2bf(a.x); u0.y = f2bf(a.y); u0.z = f2bf(a.z); u0.w = f2bf(a.w);
            u1.x = f2bf(c.x); u1.y = f2bf(c.y); u1.z = f2bf(c.z); u1.w = f2bf(c.w);
        }
        unsigned short* dst = Wp + ((size_t)b * 128 + i) * 8;   // (chunk*64+ke)*128 + i
        ((ushort4*)dst)[0] = u0;
        ((ushort4*)dst)[1] = u1;
        if (ke == 0) wsB[R] = bval;    // one thread per row writes bias (i == row)
    } else {
        // hidden packing (R7-verified): one thread per 16B frag
        int t = (b - WFRAG_BLOCKS) * 128 + i;       // 0 .. 565247
        int tau_all = t >> 13;                      // tile index, 0..68
        int e = t & 8191;
        int tok = e & 127;
        int ke = e >> 7;
        int k0 = (ke >> 3) * 64 + ((ke >> 2) & 1) * 32 + (ke & 3) * 8;
        int gtok;
        unsigned short* dst;
        if (tau_all < HP_TILES) {
            gtok = tau_all * 128 + tok;
            dst = Hp + (size_t)t * 8;
        } else {
            int pos = (tau_all - HP_TILES) * 128 + tok;
            gtok = perm[pos];
            dst = Hcp + (size_t)(t - HP_TILES * 8192) * 8;
        }
        ushort4 u0 = {0, 0, 0, 0}, u1 = {0, 0, 0, 0};
        if (gtok >= 0) {
            const float4* src = (const float4*)(hidden + (size_t)gtok * D + k0);
            float4 a = src[0], c = src[1];
            u0.x = f2bf(a.x); u0.y = f2bf(a.y); u0.z = f2bf(a.z); u0.w = f2bf(a.w);
            u1.x = f2bf(c.x); u1.y = f2bf(c.y); u1.z = f2bf(c.z); u1.w = f2bf(c.w);
        }
        ((ushort4*)dst)[0] = u0;
        ((ushort4*)dst)[1] = u1;
    }
}

// ---------------- exact fp32 dots for the two needed logits ----------------
__global__ __launch_bounds__(256) void k_stash(
    const float* __restrict__ hidden, const int* __restrict__ target,
    const float* __restrict__ weight, const float* __restrict__ bias,
    const float* __restrict__ cweight, const float* __restrict__ cbias,
    float2* __restrict__ stash)
{
    const int wave = threadIdx.x >> 6, lane = threadIdx.x & 63;
    const int t = blockIdx.x * 4 + wave;
    const int tg = target[t];
    const int ci = (tg >= 5000) + (tg >= 15000) + (tg >= 30000);
    const float4* h = (const float4*)(hidden + (size_t)t * D);
    const float4* w = (const float4*)(weight + (size_t)tg * D);
    const float4* c = (const float4*)(cweight + (size_t)(ci ? 3 - ci : 0) * D);
    float dw = 0.f, dc = 0.f;
    #pragma unroll
    for (int u = 0; u < 2; ++u) {
        float4 hh = h[lane * 2 + u];
        float4 ww = w[lane * 2 + u];
        float4 cc = c[lane * 2 + u];
        dw += hh.x * ww.x + hh.y * ww.y + hh.z * ww.z + hh.w * ww.w;
        dc += hh.x * cc.x + hh.y * cc.y + hh.z * cc.z + hh.w * cc.w;
    }
    #pragma unroll
    for (int off = 1; off < 64; off <<= 1) {
        dw += __shfl_xor(dw, off, 64);
        dc += __shfl_xor(dc, off, 64);
    }
    if (lane == 0) {
        float head = ci ? dc + cbias[3 - ci] : dw + bias[tg];
        float tail = ci ? dw + bias[tg]      : 0.f;
        stash[t] = make_float2(head, tail);
    }
}

// ---------------- barrier-free 128x128 GEMM + per-chunk LSE partial ----------------
// 256 threads = 4 waves (2Mx2N). All operands via coalesced 16B global loads
// from packed tiles (L2-resident); no LDS/barriers in K-loop -> compiler
// software-pipelines freely across the fully-unrolled 16 steps.
__global__ __launch_bounds__(256, 3) void k_gemm_all(
    const unsigned short* __restrict__ Wp, const float* __restrict__ wsB,
    const unsigned short* __restrict__ Hp, const unsigned short* __restrict__ Hcp,
    float2* __restrict__ headP, float2* __restrict__ tailP,
    const int* __restrict__ meta)
{
    // 12672 = 8 * 1584: give each XCD a contiguous chunk-major work range
    const int work = (blockIdx.x & 7) * 1584 + (blockIdx.x >> 3);
    int p, chunk, tau;
    if (work < 1280)      { p = 0; chunk = work >> 5;          tau = work & 31; }
    else if (work < 3808) { p = 1; chunk = (work - 1280) >> 5; tau = (work - 1280) & 31; }
    else if (work < 7584) { p = 2; chunk = (work - 3808) >> 5; tau = (work - 3808) & 31; }
    else                  { p = 3; chunk = (work - 7584) >> 5; tau = (work - 7584) & 31; }

    int tokBase = 0;
    const unsigned short* Hb;
    if (p == 0) {
        Hb = Hp + (size_t)tau * 65536;
    } else {
        if (tau >= meta[5 + p]) return;     // data-dependent token-tile count
        tokBase = meta[2 + p];
        Hb = Hcp + ((size_t)(tokBase >> 7) + tau) * 65536;
    }
    const int pchunk_[4] = {0, 40, 119, 237};
    const int pstart_[4] = {0, 5120, 15232, 30336};
    const unsigned short* Ab = Wp + (size_t)(pchunk_[p] + chunk) * 65536;
    const int rowBase = pstart_[p] + chunk * 128;

    const int tid = threadIdx.x;
    const int w = tid >> 6, lane = tid & 63;
    const int wm = w >> 1, wn = w & 1;
    const int lm = lane & 15, kg = lane >> 4;

    __shared__ float2 sred[2][128];

    f32x4 acc[4][4];
    #pragma unroll
    for (int m = 0; m < 4; ++m)
        #pragma unroll
        for (int n = 0; n < 4; ++n) acc[m][n] = (f32x4){0.f, 0.f, 0.f, 0.f};

    const int aLane = kg * 1024 + (wm * 64 + lm) * 8;   // frag16 = ke*128 + row
    const int bLane = kg * 1024 + (wn * 64 + lm) * 8;

    #pragma unroll
    for (int s = 0; s < 8; ++s) {
        #pragma unroll
        for (int ks = 0; ks < 2; ++ks) {
            const unsigned short* Ap = Ab + (s * 2 + ks) * 4096 + aLane;
            const unsigned short* Bp = Hb + (s * 2 + ks) * 4096 + bLane;
            short8 a4[4], b4[4];
            #pragma unroll
            for (int m = 0; m < 4; ++m)
                a4[m] = *(const short8*)(Ap + m * 128);
            #pragma unroll
            for (int n = 0; n < 4; ++n)
                b4[n] = *(const short8*)(Bp + n * 128);
            #pragma unroll
            for (int m = 0; m < 4; ++m)
                #pragma unroll
                for (int n = 0; n < 4; ++n)
                    acc[m][n] = __builtin_amdgcn_mfma_f32_16x16x32_bf16(a4[m], b4[n], acc[m][n], 0, 0, 0);
        }
    }

    // epilogue: bias + per-token LSE over this chunk's 128 rows
    f32x4 bb[4];
    #pragma unroll
    for (int m = 0; m < 4; ++m)
        bb[m] = *(const f32x4*)(wsB + rowBase + wm * 64 + m * 16 + kg * 4);

    #pragma unroll
    for (int n = 0; n < 4; ++n) {
        float mval = -1e30f;
        #pragma unroll
        for (int m = 0; m < 4; ++m)
            #pragma unroll
            for (int j = 0; j < 4; ++j) {
                acc[m][n][j] += bb[m][j];
                mval = fmaxf(mval, acc[m][n][j]);
            }
        float sval = 0.f;
        #pragma unroll
        for (int m = 0; m < 4; ++m)
            #pragma unroll
            for (int j = 0; j < 4; ++j)
                sval += __expf(acc[m][n][j] - mval);
        #pragma unroll
        for (int off = 16; off < 64; off <<= 1) {
            float m2 = __shfl_xor(mval, off, 64);
            float s2 = __shfl_xor(sval, off, 64);
            float M = fmaxf(mval, m2);
            sval = sval * __expf(mval - M) + s2 * __expf(m2 - M);
            mval = M;
        }
        if (lane < 16)
            sred[wm][wn * 64 + n * 16 + lane] = make_float2(mval, sval);
    }
    __syncthreads();
    if (tid < 128) {
        float2 p0 = sred[0][tid], p1 = sred[1][tid];
        float M = fmaxf(p0.x, p1.x);
        float S = p0.y * __expf(p0.x - M) + p1.y * __expf(p1.x - M);
        if (p == 0)
            headP[(size_t)(tau * 128 + tid) * HEAD_CHUNKS + chunk] = make_float2(M, S);
        else
            tailP[(size_t)(tokBase + tau * 128 + tid) * TAILP_STRIDE + chunk] = make_float2(M, S);
    }
}

// ---------------- merge partials -> nll ----------------
__global__ __launch_bounds__(256) void k_stageB(
    const float2* __restrict__ headP, const float2* __restrict__ tailP,
    const float2* __restrict__ stash, const int* __restrict__ target,
    const int* __restrict__ inv, float* __restrict__ out)
{
    const int wave = threadIdx.x >> 6, lane = threadIdx.x & 63;
    const int t = blockIdx.x * 4 + wave;
    const int tg = target[t];
    const int ci = (tg >= 5000) + (tg >= 15000) + (tg >= 30000);

    float m = -1e30f, s = 0.f;
    if (lane < HEAD_CHUNKS) { float2 p = headP[(size_t)t * HEAD_CHUNKS + lane]; m = p.x; s = p.y; }
    #pragma unroll
    for (int off = 1; off < 64; off <<= 1) {
        float m2 = __shfl_xor(m, off, 64);
        float s2 = __shfl_xor(s, off, 64);
        float M = fmaxf(m, m2);
        s = s * __expf(m - M) + s2 * __expf(m2 - M);
        m = M;
    }
    float2 st = stash[t];
    float nll = (m + __logf(s)) - st.x;

    if (ci) {
        const int nch_[4] = {0, 79, 118, 159};
        const int nch = nch_[ci];
        const int pos = inv[t];
        float m2 = -1e30f, s2 = 0.f;
        for (int c = lane; c < nch; c += 64) {
            float2 p = tailP[(size_t)pos * TAILP_STRIDE + c];
            float M = fmaxf(m2, p.x);
            s2 = s2 * __expf(m2 - M) + p.y * __expf(p.x - M);
            m2 = M;
        }
        #pragma unroll
        for (int off = 1; off < 64; off <<= 1) {
            float mm = __shfl_xor(m2, off, 64);
            float ss = __shfl_xor(s2, off, 64);
            float M = fmaxf(m2, mm);
            s2 = s2 * __expf(m2 - M) + ss * __expf(mm - M);
            m2 = M;
        }
        nll += (m2 + __logf(s2)) - st.y;
    }
    if (lane == 0) out[t] = nll;
}

extern "C" void kernel_launch(void* const* d_in, const int* in_sizes, int n_in,
                              void* d_out, int out_size, void* d_ws, size_t ws_size,
                              hipStream_t stream) {
    const float* hidden  = (const float*)d_in[0];
    const int*   targetp = (const int*)d_in[1];
    const float* weight  = (const float*)d_in[2];
    const float* biasp   = (const float*)d_in[3];
    const float* cweight = (const float*)d_in[4];
    const float* cbias   = (const float*)d_in[5];
    float* outp = (float*)d_out;

    char* ws = (char*)d_ws;
    unsigned short* Wp    = (unsigned short*)(ws);                 // 51,904,512 B (packed)
    float*          wsB   = (float*)(ws + 51904512);               //    202,752 B
    unsigned short* Hp    = (unsigned short*)(ws + 52107264);      //  4,194,304 B (32 tiles)
    unsigned short* Hcp   = (unsigned short*)(ws + 56301568);      //  4,849,664 B (37 tiles)
    float2*         headP = (float2*)(ws + 61151232);              //  1,310,720 B
    float2*         tailP = (float2*)(ws + 62461952);              //  6,062,080 B
    float2*         wsS   = (float2*)(ws + 68524032);              //     32,768 B
    int*            perm  = (int*)(ws + 68556800);                 //     18,944 B
    int*            inv   = (int*)(ws + 68575744);                 //     16,384 B
    int*            meta  = (int*)(ws + 68592128);                 //         64 B

    k_bucket<<<1, 256, 0, stream>>>(targetp, perm, inv, meta);
    k_convert<<<WFRAG_BLOCKS + 4416, 128, 0, stream>>>(
        weight, biasp, cweight, cbias, hidden, perm, Wp, wsB, Hp, Hcp);
    k_stash<<<NTOK / 4, 256, 0, stream>>>(hidden, targetp, weight, biasp,
                                          cweight, cbias, wsS);
    k_gemm_all<<<12672, 256, 0, stream>>>(Wp, wsB, Hp, Hcp, headP, tailP, meta);
    k_stageB<<<NTOK / 4, 256, 0, stream>>>(headP, tailP, wsS, targetp, inv, outp);
}

// Round 9
// 295.261 us; speedup vs baseline: 1.2576x; 1.2576x over previous
//
#include <hip/hip_runtime.h>

// Adaptive softmax NLL — R3's verified 128x128 BK=64 LDS-staged GEMM body,
// merged into ONE launch (flat decode + XCD-contiguous remap, early-exit).
//
// Padded reordered weight (bf16) in ws (128-row chunks):
//   head : rows [0,5120)      = weight[0:5000] ++ cluster_weight ++ pad (40 chunks)
//   tail1: rows [5120,15232)  = weight[5000:15000]  ++ pad (79 chunks)
//   tail2: rows [15232,30336) = weight[15000:30000] ++ pad (118 chunks)
//   tail3: rows [30336,50688) = weight[30000:50257] ++ pad (159 chunks)
// Pad rows: w=0, bias=-1e30 (vanish in exp-weighted LSE merges).

#define D 512
#define NROWS_PAD 50688
#define NTOK 4096
#define NTOKP 4736
#define HEAD_CHUNKS 40
#define TAILP_STRIDE 160

typedef __attribute__((ext_vector_type(8))) short short8;
typedef __attribute__((ext_vector_type(4))) float f32x4;

__device__ __forceinline__ unsigned short f2bf(float f) {
    unsigned int u = __float_as_uint(f);
    u += 0x7FFFu + ((u >> 16) & 1u);
    return (unsigned short)(u >> 16);
}

__device__ __forceinline__ void gload_lds16(const void* g, void* l) {
    __builtin_amdgcn_global_load_lds(
        (const __attribute__((address_space(1))) unsigned int*)g,
        (__attribute__((address_space(3))) unsigned int*)l, 16, 0, 0);
}

// ---------------- bucket tokens by cluster (deterministic counting sort) ----------------
__global__ __launch_bounds__(256) void k_bucket(
    const int* __restrict__ target, int* __restrict__ perm,
    int* __restrict__ inv, int* __restrict__ meta)
{
    __shared__ int cnt[256][4];
    __shared__ int basesh[256][4];
    __shared__ int sTot[4], sOff[4];
    const int th = threadIdx.x;
    for (int p = th; p < NTOKP; p += 256) perm[p] = -1;
    int lc[4] = {0, 0, 0, 0};
    #pragma unroll
    for (int i = 0; i < 16; ++i) {
        int tg = target[th * 16 + i];
        int c = (tg >= 5000) + (tg >= 15000) + (tg >= 30000);
        lc[c]++;
    }
    #pragma unroll
    for (int c = 0; c < 4; ++c) cnt[th][c] = lc[c];
    __syncthreads();
    if (th < 4) {
        int tot = 0;
        for (int i = 0; i < 256; ++i) tot += cnt[i][th];
        sTot[th] = tot;
    }
    __syncthreads();
    if (th == 0) {
        int b = 0;
        for (int c = 1; c < 4; ++c) { sOff[c] = b; b += ((sTot[c] + 127) >> 7) << 7; }
        meta[0] = sTot[1]; meta[1] = sTot[2]; meta[2] = sTot[3];
        meta[3] = sOff[1]; meta[4] = sOff[2]; meta[5] = sOff[3];
        meta[6] = (sTot[1] + 127) >> 7;
        meta[7] = (sTot[2] + 127) >> 7;
        meta[8] = (sTot[3] + 127) >> 7;
    }
    __syncthreads();
    if (th >= 1 && th < 4) {
        int run = sOff[th];
        for (int i = 0; i < 256; ++i) { basesh[i][th] = run; run += cnt[i][th]; }
    }
    __syncthreads();
    int run[4];
    #pragma unroll
    for (int c = 1; c < 4; ++c) run[c] = basesh[th][c];
    for (int i = 0; i < 16; ++i) {
        int t = th * 16 + i;
        int tg = target[t];
        int c = (tg >= 5000) + (tg >= 15000) + (tg >= 30000);
        if (c > 0) { int pos = run[c]++; perm[pos] = t; inv[t] = pos; }
        else inv[t] = -1;
    }
}

// ---------------- convert / reorder / pad / gather ----------------
__global__ __launch_bounds__(128) void k_convert(
    const float* __restrict__ weight, const float* __restrict__ bias,
    const float* __restrict__ cweight, const float* __restrict__ cbias,
    const float* __restrict__ hidden, const int* __restrict__ perm,
    unsigned short* __restrict__ wsW, float* __restrict__ wsB,
    unsigned short* __restrict__ wsH, unsigned short* __restrict__ wsHc)
{
    const int r = blockIdx.x;
    const int i = threadIdx.x;   // 0..127, one float4 each
    if (r < NROWS_PAD) {
        const int pstart[4] = {0, 5120, 15232, 30336};
        const int plen[4]   = {5003, 10000, 15000, 20257};
        const int psrc[4]   = {0, 5000, 15000, 30000};
        int p = (r < 5120) ? 0 : (r < 15232) ? 1 : (r < 30336) ? 2 : 3;
        int o = r - pstart[p];
        const float* src = nullptr;
        float b = -1e30f;
        if (o < plen[p]) {
            if (p == 0 && o >= 5000) { src = cweight + (size_t)(o - 5000) * D; b = cbias[o - 5000]; }
            else { int sr = psrc[p] + o; src = weight + (size_t)sr * D; b = bias[sr]; }
        }
        float4 v = src ? ((const float4*)src)[i] : make_float4(0.f, 0.f, 0.f, 0.f);
        ushort4 u;
        u.x = f2bf(v.x); u.y = f2bf(v.y); u.z = f2bf(v.z); u.w = f2bf(v.w);
        ((ushort4*)(wsW + (size_t)r * D))[i] = u;
        if (i == 0) wsB[r] = b;
    } else if (r < NROWS_PAD + NTOK) {
        int hr = r - NROWS_PAD;
        float4 v = ((const float4*)(hidden + (size_t)hr * D))[i];
        ushort4 u;
        u.x = f2bf(v.x); u.y = f2bf(v.y); u.z = f2bf(v.z); u.w = f2bf(v.w);
        ((ushort4*)(wsH + (size_t)hr * D))[i] = u;
    } else {
        int p = r - NROWS_PAD - NTOK;       // compacted position
        int tok = perm[p];
        float4 v = (tok >= 0) ? ((const float4*)(hidden + (size_t)tok * D))[i]
                              : make_float4(0.f, 0.f, 0.f, 0.f);
        ushort4 u;
        u.x = f2bf(v.x); u.y = f2bf(v.y); u.z = f2bf(v.z); u.w = f2bf(v.w);
        ((ushort4*)(wsHc + (size_t)p * D))[i] = u;
    }
}

// ---------------- exact fp32 dots for the two needed logits ----------------
__global__ __launch_bounds__(256) void k_stash(
    const float* __restrict__ hidden, const int* __restrict__ target,
    const float* __restrict__ weight, const float* __restrict__ bias,
    const float* __restrict__ cweight, const float* __restrict__ cbias,
    float2* __restrict__ stash)
{
    const int wave = threadIdx.x >> 6, lane = threadIdx.x & 63;
    const int t = blockIdx.x * 4 + wave;
    const int tg = target[t];
    const int ci = (tg >= 5000) + (tg >= 15000) + (tg >= 30000);
    const float4* h = (const float4*)(hidden + (size_t)t * D);
    const float4* w = (const float4*)(weight + (size_t)tg * D);
    const float4* c = (const float4*)(cweight + (size_t)(ci ? 3 - ci : 0) * D);
    float dw = 0.f, dc = 0.f;
    #pragma unroll
    for (int u = 0; u < 2; ++u) {
        float4 hh = h[lane * 2 + u];
        float4 ww = w[lane * 2 + u];
        float4 cc = c[lane * 2 + u];
        dw += hh.x * ww.x + hh.y * ww.y + hh.z * ww.z + hh.w * ww.w;
        dc += hh.x * cc.x + hh.y * cc.y + hh.z * cc.z + hh.w * cc.w;
    }
    #pragma unroll
    for (int off = 1; off < 64; off <<= 1) {
        dw += __shfl_xor(dw, off, 64);
        dc += __shfl_xor(dc, off, 64);
    }
    if (lane == 0) {
        float head = ci ? dc + cbias[3 - ci] : dw + bias[tg];
        float tail = ci ? dw + bias[tg]      : 0.f;
        stash[t] = make_float2(head, tail);
    }
}

// ---------------- merged R3-body GEMM: 128x128, BK=64, dual gload_lds ----------------
// Flat decode bid -> (partition, chunk, token-tile); XCD-contiguous remap keeps
// one weight slab per XCD L2. Inner loop identical to R3 (212us champion).
__global__ __launch_bounds__(256) void k_gemm_all(
    const unsigned short* __restrict__ wsW, const float* __restrict__ wsB,
    const unsigned short* __restrict__ wsH, const unsigned short* __restrict__ wsHc,
    float2* __restrict__ headP, float2* __restrict__ tailP,
    const int* __restrict__ meta)
{
    // 12672 = 8 * 1584: each XCD gets a contiguous chunk-major work range
    const int work = (blockIdx.x & 7) * 1584 + (blockIdx.x >> 3);
    int p, chunk, tau;
    if (work < 1280)      { p = 0; chunk = work >> 5; }
    else if (work < 3808) { p = 1; chunk = (work - 1280) >> 5; }
    else if (work < 7584) { p = 2; chunk = (work - 3808) >> 5; }
    else                  { p = 3; chunk = (work - 7584) >> 5; }
    tau = work & 31;

    int tokBase = 0;
    const unsigned short* H = wsH;
    if (p > 0) {
        if (tau >= meta[5 + p]) return;   // data-dependent token-tile count
        tokBase = meta[2 + p];
        H = wsHc;
    }
    const int pstart_[4] = {0, 5120, 15232, 30336};
    const int rowBase = pstart_[p] + chunk * 128;

    const int tid = threadIdx.x;
    const int w = tid >> 6, lane = tid & 63;
    const int wm = w >> 1, wn = w & 1;

    __shared__ unsigned short ldsA[2][128 * 64];
    __shared__ unsigned short ldsB[2][128 * 64];
    __shared__ float2 sred[2][128];

    const unsigned short* Wb = wsW + (size_t)rowBase * D;
    const unsigned short* Hb = H + (size_t)(tokBase + tau * 128) * D;

    f32x4 acc[4][4];
    #pragma unroll
    for (int m = 0; m < 4; ++m)
        #pragma unroll
        for (int n = 0; n < 4; ++n) acc[m][n] = (f32x4){0.f, 0.f, 0.f, 0.f};

    const int eBase = w * 256 + lane;

    auto STAGE = [&](int buf, int t) {
        #pragma unroll
        for (int j = 0; j < 4; ++j) {
            int e = eBase + j * 64;
            int r = e >> 3;
            int ck = (e & 7) ^ (r & 7);                 // inverse-swizzled source chunk
            size_t go = (size_t)r * D + (size_t)t * 64 + ck * 8;
            gload_lds16(Wb + go, &ldsA[buf][(w * 4 + j) * 512]);
            gload_lds16(Hb + go, &ldsB[buf][(w * 4 + j) * 512]);
        }
    };

    STAGE(0, 0);
    __syncthreads();

    const int xorv = (lane & 7) << 4;          // byte XOR for swizzled read
    const int rowA = wm * 64 + (lane & 15);
    const int rowB = wn * 64 + (lane & 15);
    const int kbase = (lane >> 4) * 16;        // byte offset within 32-k step

    int buf = 0;
    for (int t = 0; t < 8; ++t) {
        if (t < 7) STAGE(buf ^ 1, t + 1);
        #pragma unroll
        for (int ks = 0; ks < 2; ++ks) {
            const int koff = (ks * 64 + kbase) ^ xorv;
            short8 af[4], bfr[4];
            #pragma unroll
            for (int m = 0; m < 4; ++m)
                af[m] = *(const short8*)((const char*)&ldsA[buf][0] + (rowA + m * 16) * 128 + koff);
            #pragma unroll
            for (int n = 0; n < 4; ++n)
                bfr[n] = *(const short8*)((const char*)&ldsB[buf][0] + (rowB + n * 16) * 128 + koff);
            #pragma unroll
            for (int m = 0; m < 4; ++m)
                #pragma unroll
                for (int n = 0; n < 4; ++n)
                    acc[m][n] = __builtin_amdgcn_mfma_f32_16x16x32_bf16(af[m], bfr[n], acc[m][n], 0, 0, 0);
        }
        __syncthreads();
        buf ^= 1;
    }

    // epilogue: bias + per-token LSE over this chunk's 128 rows
    const int rg = lane >> 4;
    f32x4 bb[4];
    #pragma unroll
    for (int m = 0; m < 4; ++m)
        bb[m] = *(const f32x4*)(wsB + rowBase + wm * 64 + m * 16 + rg * 4);

    #pragma unroll
    for (int n = 0; n < 4; ++n) {
        float mval = -1e30f;
        #pragma unroll
        for (int m = 0; m < 4; ++m)
            #pragma unroll
            for (int j = 0; j < 4; ++j) {
                acc[m][n][j] += bb[m][j];
                mval = fmaxf(mval, acc[m][n][j]);
            }
        float sval = 0.f;
        #pragma unroll
        for (int m = 0; m < 4; ++m)
            #pragma unroll
            for (int j = 0; j < 4; ++j)
                sval += __expf(acc[m][n][j] - mval);
        #pragma unroll
        for (int off = 16; off < 64; off <<= 1) {
            float m2 = __shfl_xor(mval, off, 64);
            float s2 = __shfl_xor(sval, off, 64);
            float M = fmaxf(mval, m2);
            sval = sval * __expf(mval - M) + s2 * __expf(m2 - M);
            mval = M;
        }
        if (lane < 16)
            sred[wm][wn * 64 + n * 16 + lane] = make_float2(mval, sval);
    }
    __syncthreads();
    if (tid < 128) {
        float2 p0 = sred[0][tid], p1 = sred[1][tid];
        float M = fmaxf(p0.x, p1.x);
        float S = p0.y * __expf(p0.x - M) + p1.y * __expf(p1.x - M);
        if (p == 0)
            headP[(size_t)(tau * 128 + tid) * HEAD_CHUNKS + chunk] = make_float2(M, S);
        else
            tailP[(size_t)(tokBase + tau * 128 + tid) * TAILP_STRIDE + chunk] = make_float2(M, S);
    }
}

// ---------------- merge partials -> nll ----------------
__global__ __launch_bounds__(256) void k_stageB(
    const float2* __restrict__ headP, const float2* __restrict__ tailP,
    const float2* __restrict__ stash, const int* __restrict__ target,
    const int* __restrict__ inv, float* __restrict__ out)
{
    const int wave = threadIdx.x >> 6, lane = threadIdx.x & 63;
    const int t = blockIdx.x * 4 + wave;
    const int tg = target[t];
    const int ci = (tg >= 5000) + (tg >= 15000) + (tg >= 30000);

    float m = -1e30f, s = 0.f;
    if (lane < HEAD_CHUNKS) { float2 p = headP[(size_t)t * HEAD_CHUNKS + lane]; m = p.x; s = p.y; }
    #pragma unroll
    for (int off = 1; off < 64; off <<= 1) {
        float m2 = __shfl_xor(m, off, 64);
        float s2 = __shfl_xor(s, off, 64);
        float M = fmaxf(m, m2);
        s = s * __expf(m - M) + s2 * __expf(m2 - M);
        m = M;
    }
    float2 st = stash[t];
    float nll = (m + __logf(s)) - st.x;

    if (ci) {
        const int nch_[4] = {0, 79, 118, 159};
        const int nch = nch_[ci];
        const int pos = inv[t];
        float m2 = -1e30f, s2 = 0.f;
        for (int c = lane; c < nch; c += 64) {
            float2 p = tailP[(size_t)pos * TAILP_STRIDE + c];
            float M = fmaxf(m2, p.x);
            s2 = s2 * __expf(m2 - M) + p.y * __expf(p.x - M);
            m2 = M;
        }
        #pragma unroll
        for (int off = 1; off < 64; off <<= 1) {
            float mm = __shfl_xor(m2, off, 64);
            float ss = __shfl_xor(s2, off, 64);
            float M = fmaxf(m2, mm);
            s2 = s2 * __expf(m2 - M) + ss * __expf(mm - M);
            m2 = M;
        }
        nll += (m2 + __logf(s2)) - st.y;
    }
    if (lane == 0) out[t] = nll;
}

extern "C" void kernel_launch(void* const* d_in, const int* in_sizes, int n_in,
                              void* d_out, int out_size, void* d_ws, size_t ws_size,
                              hipStream_t stream) {
    const float* hidden  = (const float*)d_in[0];
    const int*   targetp = (const int*)d_in[1];
    const float* weight  = (const float*)d_in[2];
    const float* biasp   = (const float*)d_in[3];
    const float* cweight = (const float*)d_in[4];
    const float* cbias   = (const float*)d_in[5];
    float* outp = (float*)d_out;

    char* ws = (char*)d_ws;
    unsigned short* wsW   = (unsigned short*)(ws);                 // 51,904,512 B
    float*          wsB   = (float*)(ws + 51904512);               //    202,752 B
    unsigned short* wsH   = (unsigned short*)(ws + 52107264);      //  4,194,304 B
    unsigned short* wsHc  = (unsigned short*)(ws + 56301568);      //  4,849,664 B
    float2*         headP = (float2*)(ws + 61151232);              //  1,310,720 B
    float2*         tailP = (float2*)(ws + 62461952);              //  6,062,080 B
    float2*         wsS   = (float2*)(ws + 68524032);              //     32,768 B
    int*            perm  = (int*)(ws + 68556800);                 //     18,944 B
    int*            inv   = (int*)(ws + 68575744);                 //     16,384 B
    int*            meta  = (int*)(ws + 68592128);                 //         64 B

    k_bucket<<<1, 256, 0, stream>>>(targetp, perm, inv, meta);
    k_convert<<<NROWS_PAD + NTOK + NTOKP, 128, 0, stream>>>(
        weight, biasp, cweight, cbias, hidden, perm, wsW, wsB, wsH, wsHc);
    k_stash<<<NTOK / 4, 256, 0, stream>>>(hidden, targetp, weight, biasp,
                                          cweight, cbias, wsS);
    k_gemm_all<<<12672, 256, 0, stream>>>(wsW, wsB, wsH, wsHc, headP, tailP, meta);
    k_stageB<<<NTOK / 4, 256, 0, stream>>>(headP, tailP, wsS, targetp, inv, outp);
}

// Round 10
// 172.426 us; speedup vs baseline: 2.1535x; 1.7124x over previous
//
#include <hip/hip_runtime.h>

// Adaptive softmax NLL — R3's verified 128x128 BK=64 LDS-staged GEMM body,
// persistent-CTA work distribution (exact item count from meta, grid-stride).
//
// Padded reordered weight (bf16) in ws (128-row chunks):
//   head : rows [0,5120)      = weight[0:5000] ++ cluster_weight ++ pad (40 chunks)
//   tail1: rows [5120,15232)  = weight[5000:15000]  ++ pad (79 chunks)
//   tail2: rows [15232,30336) = weight[15000:30000] ++ pad (118 chunks)
//   tail3: rows [30336,50688) = weight[30000:50257] ++ pad (159 chunks)
// Pad rows: w=0, bias=-1e30 (vanish in exp-weighted LSE merges).
// Work item = (partition, chunk, token-tile), chunk-major (tau fastest),
// only REAL tiles enumerated -> perfect balance, no early-exit duds.

#define D 512
#define NROWS_PAD 50688
#define NTOK 4096
#define NTOKP 4736
#define HEAD_CHUNKS 40
#define TAILP_STRIDE 160
#define GRID_PERSIST 512

typedef __attribute__((ext_vector_type(8))) short short8;
typedef __attribute__((ext_vector_type(4))) float f32x4;

__device__ __forceinline__ unsigned short f2bf(float f) {
    unsigned int u = __float_as_uint(f);
    u += 0x7FFFu + ((u >> 16) & 1u);
    return (unsigned short)(u >> 16);
}

__device__ __forceinline__ void gload_lds16(const void* g, void* l) {
    __builtin_amdgcn_global_load_lds(
        (const __attribute__((address_space(1))) unsigned int*)g,
        (__attribute__((address_space(3))) unsigned int*)l, 16, 0, 0);
}

// ---------------- bucket tokens by cluster (deterministic counting sort) ----------------
__global__ __launch_bounds__(256) void k_bucket(
    const int* __restrict__ target, int* __restrict__ perm,
    int* __restrict__ inv, int* __restrict__ meta)
{
    __shared__ int cnt[256][4];
    __shared__ int basesh[256][4];
    __shared__ int sTot[4], sOff[4];
    const int th = threadIdx.x;
    for (int p = th; p < NTOKP; p += 256) perm[p] = -1;
    int lc[4] = {0, 0, 0, 0};
    #pragma unroll
    for (int i = 0; i < 16; ++i) {
        int tg = target[th * 16 + i];
        int c = (tg >= 5000) + (tg >= 15000) + (tg >= 30000);
        lc[c]++;
    }
    #pragma unroll
    for (int c = 0; c < 4; ++c) cnt[th][c] = lc[c];
    __syncthreads();
    if (th < 4) {
        int tot = 0;
        for (int i = 0; i < 256; ++i) tot += cnt[i][th];
        sTot[th] = tot;
    }
    __syncthreads();
    if (th == 0) {
        int b = 0;
        for (int c = 1; c < 4; ++c) { sOff[c] = b; b += ((sTot[c] + 127) >> 7) << 7; }
        meta[0] = sTot[1]; meta[1] = sTot[2]; meta[2] = sTot[3];
        meta[3] = sOff[1]; meta[4] = sOff[2]; meta[5] = sOff[3];
        meta[6] = (sTot[1] + 127) >> 7;
        meta[7] = (sTot[2] + 127) >> 7;
        meta[8] = (sTot[3] + 127) >> 7;
    }
    __syncthreads();
    if (th >= 1 && th < 4) {
        int run = sOff[th];
        for (int i = 0; i < 256; ++i) { basesh[i][th] = run; run += cnt[i][th]; }
    }
    __syncthreads();
    int run[4];
    #pragma unroll
    for (int c = 1; c < 4; ++c) run[c] = basesh[th][c];
    for (int i = 0; i < 16; ++i) {
        int t = th * 16 + i;
        int tg = target[t];
        int c = (tg >= 5000) + (tg >= 15000) + (tg >= 30000);
        if (c > 0) { int pos = run[c]++; perm[pos] = t; inv[t] = pos; }
        else inv[t] = -1;
    }
}

// ---------------- convert / reorder / pad / gather ----------------
__global__ __launch_bounds__(128) void k_convert(
    const float* __restrict__ weight, const float* __restrict__ bias,
    const float* __restrict__ cweight, const float* __restrict__ cbias,
    const float* __restrict__ hidden, const int* __restrict__ perm,
    unsigned short* __restrict__ wsW, float* __restrict__ wsB,
    unsigned short* __restrict__ wsH, unsigned short* __restrict__ wsHc)
{
    const int r = blockIdx.x;
    const int i = threadIdx.x;   // 0..127, one float4 each
    if (r < NROWS_PAD) {
        const int pstart[4] = {0, 5120, 15232, 30336};
        const int plen[4]   = {5003, 10000, 15000, 20257};
        const int psrc[4]   = {0, 5000, 15000, 30000};
        int p = (r < 5120) ? 0 : (r < 15232) ? 1 : (r < 30336) ? 2 : 3;
        int o = r - pstart[p];
        const float* src = nullptr;
        float b = -1e30f;
        if (o < plen[p]) {
            if (p == 0 && o >= 5000) { src = cweight + (size_t)(o - 5000) * D; b = cbias[o - 5000]; }
            else { int sr = psrc[p] + o; src = weight + (size_t)sr * D; b = bias[sr]; }
        }
        float4 v = src ? ((const float4*)src)[i] : make_float4(0.f, 0.f, 0.f, 0.f);
        ushort4 u;
        u.x = f2bf(v.x); u.y = f2bf(v.y); u.z = f2bf(v.z); u.w = f2bf(v.w);
        ((ushort4*)(wsW + (size_t)r * D))[i] = u;
        if (i == 0) wsB[r] = b;
    } else if (r < NROWS_PAD + NTOK) {
        int hr = r - NROWS_PAD;
        float4 v = ((const float4*)(hidden + (size_t)hr * D))[i];
        ushort4 u;
        u.x = f2bf(v.x); u.y = f2bf(v.y); u.z = f2bf(v.z); u.w = f2bf(v.w);
        ((ushort4*)(wsH + (size_t)hr * D))[i] = u;
    } else {
        int p = r - NROWS_PAD - NTOK;       // compacted position
        int tok = perm[p];
        float4 v = (tok >= 0) ? ((const float4*)(hidden + (size_t)tok * D))[i]
                              : make_float4(0.f, 0.f, 0.f, 0.f);
        ushort4 u;
        u.x = f2bf(v.x); u.y = f2bf(v.y); u.z = f2bf(v.z); u.w = f2bf(v.w);
        ((ushort4*)(wsHc + (size_t)p * D))[i] = u;
    }
}

// ---------------- exact fp32 dots for the two needed logits ----------------
__global__ __launch_bounds__(256) void k_stash(
    const float* __restrict__ hidden, const int* __restrict__ target,
    const float* __restrict__ weight, const float* __restrict__ bias,
    const float* __restrict__ cweight, const float* __restrict__ cbias,
    float2* __restrict__ stash)
{
    const int wave = threadIdx.x >> 6, lane = threadIdx.x & 63;
    const int t = blockIdx.x * 4 + wave;
    const int tg = target[t];
    const int ci = (tg >= 5000) + (tg >= 15000) + (tg >= 30000);
    const float4* h = (const float4*)(hidden + (size_t)t * D);
    const float4* w = (const float4*)(weight + (size_t)tg * D);
    const float4* c = (const float4*)(cweight + (size_t)(ci ? 3 - ci : 0) * D);
    float dw = 0.f, dc = 0.f;
    #pragma unroll
    for (int u = 0; u < 2; ++u) {
        float4 hh = h[lane * 2 + u];
        float4 ww = w[lane * 2 + u];
        float4 cc = c[lane * 2 + u];
        dw += hh.x * ww.x + hh.y * ww.y + hh.z * ww.z + hh.w * ww.w;
        dc += hh.x * cc.x + hh.y * cc.y + hh.z * cc.z + hh.w * cc.w;
    }
    #pragma unroll
    for (int off = 1; off < 64; off <<= 1) {
        dw += __shfl_xor(dw, off, 64);
        dc += __shfl_xor(dc, off, 64);
    }
    if (lane == 0) {
        float head = ci ? dc + cbias[3 - ci] : dw + bias[tg];
        float tail = ci ? dw + bias[tg]      : 0.f;
        stash[t] = make_float2(head, tail);
    }
}

// ---------------- persistent-CTA merged GEMM: R3 body, exact work list ----------------
__global__ __launch_bounds__(256) void k_gemm_all(
    const unsigned short* __restrict__ wsW, const float* __restrict__ wsB,
    const unsigned short* __restrict__ wsH, const unsigned short* __restrict__ wsHc,
    float2* __restrict__ headP, float2* __restrict__ tailP,
    const int* __restrict__ meta)
{
    const int nt1 = meta[6], nt2 = meta[7], nt3 = meta[8];
    const int base1 = meta[3], base2 = meta[4], base3 = meta[5];
    const int b1 = HEAD_CHUNKS * 32;
    const int b2 = b1 + 79 * nt1;
    const int b3 = b2 + 118 * nt2;
    const int b4 = b3 + 159 * nt3;

    const int tid = threadIdx.x;
    const int w = tid >> 6, lane = tid & 63;
    const int wm = w >> 1, wn = w & 1;
    const int eBase = w * 256 + lane;
    const int xorv = (lane & 7) << 4;
    const int rowA = wm * 64 + (lane & 15);
    const int rowB = wn * 64 + (lane & 15);
    const int kbase = (lane >> 4) * 16;
    const int rg = lane >> 4;

    __shared__ unsigned short ldsA[2][128 * 64];
    __shared__ unsigned short ldsB[2][128 * 64];
    __shared__ float2 sred[2][128];

    for (int item = blockIdx.x; item < b4; item += GRID_PERSIST) {
        // ---- decode item -> (partition, chunk, tau) ----
        int p, chunk, tau, tokBase;
        const unsigned short* H;
        if (item < b1) {
            p = 0; chunk = item >> 5; tau = item & 31;
            tokBase = 0; H = wsH;
        } else if (item < b2) {
            p = 1; int idx = item - b1; chunk = idx / nt1; tau = idx - chunk * nt1;
            tokBase = base1; H = wsHc;
        } else if (item < b3) {
            p = 2; int idx = item - b2; chunk = idx / nt2; tau = idx - chunk * nt2;
            tokBase = base2; H = wsHc;
        } else {
            p = 3; int idx = item - b3; chunk = idx / nt3; tau = idx - chunk * nt3;
            tokBase = base3; H = wsHc;
        }
        const int pstart_[4] = {0, 5120, 15232, 30336};
        const int rowBase = pstart_[p] + chunk * 128;

        const unsigned short* Wb = wsW + (size_t)rowBase * D;
        const unsigned short* Hb = H + (size_t)(tokBase + tau * 128) * D;

        f32x4 acc[4][4];
        #pragma unroll
        for (int m = 0; m < 4; ++m)
            #pragma unroll
            for (int n = 0; n < 4; ++n) acc[m][n] = (f32x4){0.f, 0.f, 0.f, 0.f};

        auto STAGE = [&](int buf, int t) {
            #pragma unroll
            for (int j = 0; j < 4; ++j) {
                int e = eBase + j * 64;
                int r = e >> 3;
                int ck = (e & 7) ^ (r & 7);             // inverse-swizzled source chunk
                size_t go = (size_t)r * D + (size_t)t * 64 + ck * 8;
                gload_lds16(Wb + go, &ldsA[buf][(w * 4 + j) * 512]);
                gload_lds16(Hb + go, &ldsB[buf][(w * 4 + j) * 512]);
            }
        };

        STAGE(0, 0);
        __syncthreads();

        int buf = 0;
        for (int t = 0; t < 8; ++t) {
            if (t < 7) STAGE(buf ^ 1, t + 1);
            #pragma unroll
            for (int ks = 0; ks < 2; ++ks) {
                const int koff = (ks * 64 + kbase) ^ xorv;
                short8 af[4], bfr[4];
                #pragma unroll
                for (int m = 0; m < 4; ++m)
                    af[m] = *(const short8*)((const char*)&ldsA[buf][0] + (rowA + m * 16) * 128 + koff);
                #pragma unroll
                for (int n = 0; n < 4; ++n)
                    bfr[n] = *(const short8*)((const char*)&ldsB[buf][0] + (rowB + n * 16) * 128 + koff);
                #pragma unroll
                for (int m = 0; m < 4; ++m)
                    #pragma unroll
                    for (int n = 0; n < 4; ++n)
                        acc[m][n] = __builtin_amdgcn_mfma_f32_16x16x32_bf16(af[m], bfr[n], acc[m][n], 0, 0, 0);
            }
            __syncthreads();
            buf ^= 1;
        }

        // ---- epilogue: bias + per-token LSE over this chunk's 128 rows ----
        f32x4 bb[4];
        #pragma unroll
        for (int m = 0; m < 4; ++m)
            bb[m] = *(const f32x4*)(wsB + rowBase + wm * 64 + m * 16 + rg * 4);

        #pragma unroll
        for (int n = 0; n < 4; ++n) {
            float mval = -1e30f;
            #pragma unroll
            for (int m = 0; m < 4; ++m)
                #pragma unroll
                for (int j = 0; j < 4; ++j) {
                    acc[m][n][j] += bb[m][j];
                    mval = fmaxf(mval, acc[m][n][j]);
                }
            float sval = 0.f;
            #pragma unroll
            for (int m = 0; m < 4; ++m)
                #pragma unroll
                for (int j = 0; j < 4; ++j)
                    sval += __expf(acc[m][n][j] - mval);
            #pragma unroll
            for (int off = 16; off < 64; off <<= 1) {
                float m2 = __shfl_xor(mval, off, 64);
                float s2 = __shfl_xor(sval, off, 64);
                float M = fmaxf(mval, m2);
                sval = sval * __expf(mval - M) + s2 * __expf(m2 - M);
                mval = M;
            }
            if (lane < 16)
                sred[wm][wn * 64 + n * 16 + lane] = make_float2(mval, sval);
        }
        __syncthreads();
        if (tid < 128) {
            float2 p0 = sred[0][tid], p1 = sred[1][tid];
            float M = fmaxf(p0.x, p1.x);
            float S = p0.y * __expf(p0.x - M) + p1.y * __expf(p1.x - M);
            if (p == 0)
                headP[(size_t)(tau * 128 + tid) * HEAD_CHUNKS + chunk] = make_float2(M, S);
            else
                tailP[(size_t)(tokBase + tau * 128 + tid) * TAILP_STRIDE + chunk] = make_float2(M, S);
        }
        // LDS reuse safe: next item's first use is guarded by barriers.
    }
}

// ---------------- merge partials -> nll ----------------
__global__ __launch_bounds__(256) void k_stageB(
    const float2* __restrict__ headP, const float2* __restrict__ tailP,
    const float2* __restrict__ stash, const int* __restrict__ target,
    const int* __restrict__ inv, float* __restrict__ out)
{
    const int wave = threadIdx.x >> 6, lane = threadIdx.x & 63;
    const int t = blockIdx.x * 4 + wave;
    const int tg = target[t];
    const int ci = (tg >= 5000) + (tg >= 15000) + (tg >= 30000);

    float m = -1e30f, s = 0.f;
    if (lane < HEAD_CHUNKS) { float2 p = headP[(size_t)t * HEAD_CHUNKS + lane]; m = p.x; s = p.y; }
    #pragma unroll
    for (int off = 1; off < 64; off <<= 1) {
        float m2 = __shfl_xor(m, off, 64);
        float s2 = __shfl_xor(s, off, 64);
        float M = fmaxf(m, m2);
        s = s * __expf(m - M) + s2 * __expf(m2 - M);
        m = M;
    }
    float2 st = stash[t];
    float nll = (m + __logf(s)) - st.x;

    if (ci) {
        const int nch_[4] = {0, 79, 118, 159};
        const int nch = nch_[ci];
        const int pos = inv[t];
        float m2 = -1e30f, s2 = 0.f;
        for (int c = lane; c < nch; c += 64) {
            float2 p = tailP[(size_t)pos * TAILP_STRIDE + c];
            float M = fmaxf(m2, p.x);
            s2 = s2 * __expf(m2 - M) + p.y * __expf(p.x - M);
            m2 = M;
        }
        #pragma unroll
        for (int off = 1; off < 64; off <<= 1) {
            float mm = __shfl_xor(m2, off, 64);
            float ss = __shfl_xor(s2, off, 64);
            float M = fmaxf(m2, mm);
            s2 = s2 * __expf(m2 - M) + ss * __expf(mm - M);
            m2 = M;
        }
        nll += (m2 + __logf(s2)) - st.y;
    }
    if (lane == 0) out[t] = nll;
}

extern "C" void kernel_launch(void* const* d_in, const int* in_sizes, int n_in,
                              void* d_out, int out_size, void* d_ws, size_t ws_size,
                              hipStream_t stream) {
    const float* hidden  = (const float*)d_in[0];
    const int*   targetp = (const int*)d_in[1];
    const float* weight  = (const float*)d_in[2];
    const float* biasp   = (const float*)d_in[3];
    const float* cweight = (const float*)d_in[4];
    const float* cbias   = (const float*)d_in[5];
    float* outp = (float*)d_out;

    char* ws = (char*)d_ws;
    unsigned short* wsW   = (unsigned short*)(ws);                 // 51,904,512 B
    float*          wsB   = (float*)(ws + 51904512);               //    202,752 B
    unsigned short* wsH   = (unsigned short*)(ws + 52107264);      //  4,194,304 B
    unsigned short* wsHc  = (unsigned short*)(ws + 56301568);      //  4,849,664 B
    float2*         headP = (float2*)(ws + 61151232);              //  1,310,720 B
    float2*         tailP = (float2*)(ws + 62461952);              //  6,062,080 B
    float2*         wsS   = (float2*)(ws + 68524032);              //     32,768 B
    int*            perm  = (int*)(ws + 68556800);                 //     18,944 B
    int*            inv   = (int*)(ws + 68575744);                 //     16,384 B
    int*            meta  = (int*)(ws + 68592128);                 //         64 B

    k_bucket<<<1, 256, 0, stream>>>(targetp, perm, inv, meta);
    k_convert<<<NROWS_PAD + NTOK + NTOKP, 128, 0, stream>>>(
        weight, biasp, cweight, cbias, hidden, perm, wsW, wsB, wsH, wsHc);
    k_stash<<<NTOK / 4, 256, 0, stream>>>(hidden, targetp, weight, biasp,
                                          cweight, cbias, wsS);
    k_gemm_all<<<GRID_PERSIST, 256, 0, stream>>>(wsW, wsB, wsH, wsHc, headP, tailP, meta);
    k_stageB<<<NTOK / 4, 256, 0, stream>>>(headP, tailP, wsS, targetp, inv, outp);
}

// Round 11
// 143.929 us; speedup vs baseline: 2.5799x; 1.1980x over previous
//
#include <hip/hip_runtime.h>

// Adaptive softmax NLL — fp8(e4m3)-MFMA persistent GEMM, 4 blocks/CU,
// cross-item prefetch. Target/routing logits exact fp32 via k_stash.
//
// Packed fp8 weight in ws (128-row chunks, row = 512 B):
//   head : rows [0,5120)      = weight[0:5000] ++ cluster_weight ++ pad (40 chunks)
//   tail1: rows [5120,15232)  = weight[5000:15000]  ++ pad (79 chunks)
//   tail2: rows [15232,30336) = weight[15000:30000] ++ pad (118 chunks)
//   tail3: rows [30336,50688) = weight[30000:50257] ++ pad (159 chunks)
// Pad rows: w=0, bias=-1e30 (vanish in exp-weighted LSE merges).
// Work item = (partition, chunk, token-tile), exact list, persistent CTAs.

#define D 512
#define NROWS_PAD 50688
#define NTOK 4096
#define NTOKP 4736
#define HEAD_CHUNKS 40
#define TAILP_STRIDE 160
#define GRID_PERSIST 1024

typedef __attribute__((ext_vector_type(4))) float f32x4;

__device__ __forceinline__ unsigned f2fp8(float f) {
    // f32 -> OCP e4m3fn, RNE, saturate to 448
    unsigned u = __float_as_uint(f);
    unsigned s = (u >> 24) & 0x80u;
    unsigned a = u & 0x7FFFFFFFu;
    if (a >= 0x43E00000u) return s | 0x7Eu;          // >= 448 -> sat
    if (a < 0x3C800000u) {                            // < 2^-6 -> subnormal
        int n = __float2int_rn(__uint_as_float(a) * 512.f);
        return s | (unsigned)n;
    }
    unsigned lsb = (a >> 20) & 1u;
    a += 0x7FFFFu + lsb;                              // RNE at bit 20
    unsigned e = (a >> 23) - 120u;
    unsigned m = (a >> 20) & 7u;
    if (e >= 16u || (e == 15u && m == 7u)) return s | 0x7Eu;
    return s | (e << 3) | m;
}

__device__ __forceinline__ void gload_lds16(const void* g, void* l) {
    __builtin_amdgcn_global_load_lds(
        (const __attribute__((address_space(1))) unsigned int*)g,
        (__attribute__((address_space(3))) unsigned int*)l, 16, 0, 0);
}

// ---------------- bucket tokens by cluster (deterministic counting sort) ----------------
__global__ __launch_bounds__(256) void k_bucket(
    const int* __restrict__ target, int* __restrict__ perm,
    int* __restrict__ inv, int* __restrict__ meta)
{
    __shared__ int cnt[256][4];
    __shared__ int basesh[256][4];
    __shared__ int sTot[4], sOff[4];
    const int th = threadIdx.x;
    for (int p = th; p < NTOKP; p += 256) perm[p] = -1;
    int lc[4] = {0, 0, 0, 0};
    #pragma unroll
    for (int i = 0; i < 16; ++i) {
        int tg = target[th * 16 + i];
        int c = (tg >= 5000) + (tg >= 15000) + (tg >= 30000);
        lc[c]++;
    }
    #pragma unroll
    for (int c = 0; c < 4; ++c) cnt[th][c] = lc[c];
    __syncthreads();
    if (th < 4) {
        int tot = 0;
        for (int i = 0; i < 256; ++i) tot += cnt[i][th];
        sTot[th] = tot;
    }
    __syncthreads();
    if (th == 0) {
        int b = 0;
        for (int c = 1; c < 4; ++c) { sOff[c] = b; b += ((sTot[c] + 127) >> 7) << 7; }
        meta[0] = sTot[1]; meta[1] = sTot[2]; meta[2] = sTot[3];
        meta[3] = sOff[1]; meta[4] = sOff[2]; meta[5] = sOff[3];
        meta[6] = (sTot[1] + 127) >> 7;
        meta[7] = (sTot[2] + 127) >> 7;
        meta[8] = (sTot[3] + 127) >> 7;
    }
    __syncthreads();
    if (th >= 1 && th < 4) {
        int run = sOff[th];
        for (int i = 0; i < 256; ++i) { basesh[i][th] = run; run += cnt[i][th]; }
    }
    __syncthreads();
    int run[4];
    #pragma unroll
    for (int c = 1; c < 4; ++c) run[c] = basesh[th][c];
    for (int i = 0; i < 16; ++i) {
        int t = th * 16 + i;
        int tg = target[t];
        int c = (tg >= 5000) + (tg >= 15000) + (tg >= 30000);
        if (c > 0) { int pos = run[c]++; perm[pos] = t; inv[t] = pos; }
        else inv[t] = -1;
    }
}

// ---------------- convert to fp8 / reorder / pad / gather ----------------
__global__ __launch_bounds__(128) void k_convert(
    const float* __restrict__ weight, const float* __restrict__ bias,
    const float* __restrict__ cweight, const float* __restrict__ cbias,
    const float* __restrict__ hidden, const int* __restrict__ perm,
    unsigned char* __restrict__ wsW, float* __restrict__ wsB,
    unsigned char* __restrict__ wsH, unsigned char* __restrict__ wsHc)
{
    const int r = blockIdx.x;
    const int i = threadIdx.x;   // 0..127, one float4 -> 4 fp8 bytes each
    float4 v = make_float4(0.f, 0.f, 0.f, 0.f);
    unsigned* dst;
    if (r < NROWS_PAD) {
        const int pstart[4] = {0, 5120, 15232, 30336};
        const int plen[4]   = {5003, 10000, 15000, 20257};
        const int psrc[4]   = {0, 5000, 15000, 30000};
        int p = (r < 5120) ? 0 : (r < 15232) ? 1 : (r < 30336) ? 2 : 3;
        int o = r - pstart[p];
        const float* src = nullptr;
        float b = -1e30f;
        if (o < plen[p]) {
            if (p == 0 && o >= 5000) { src = cweight + (size_t)(o - 5000) * D; b = cbias[o - 5000]; }
            else { int sr = psrc[p] + o; src = weight + (size_t)sr * D; b = bias[sr]; }
        }
        if (src) v = ((const float4*)src)[i];
        if (i == 0) wsB[r] = b;
        dst = (unsigned*)(wsW + (size_t)r * D);
    } else if (r < NROWS_PAD + NTOK) {
        int hr = r - NROWS_PAD;
        v = ((const float4*)(hidden + (size_t)hr * D))[i];
        dst = (unsigned*)(wsH + (size_t)hr * D);
    } else {
        int p = r - NROWS_PAD - NTOK;       // compacted position
        int tok = perm[p];
        if (tok >= 0) v = ((const float4*)(hidden + (size_t)tok * D))[i];
        dst = (unsigned*)(wsHc + (size_t)p * D);
    }
    unsigned pk = f2fp8(v.x) | (f2fp8(v.y) << 8) | (f2fp8(v.z) << 16) | (f2fp8(v.w) << 24);
    dst[i] = pk;
}

// ---------------- exact fp32 dots for the two needed logits ----------------
__global__ __launch_bounds__(256) void k_stash(
    const float* __restrict__ hidden, const int* __restrict__ target,
    const float* __restrict__ weight, const float* __restrict__ bias,
    const float* __restrict__ cweight, const float* __restrict__ cbias,
    float2* __restrict__ stash)
{
    const int wave = threadIdx.x >> 6, lane = threadIdx.x & 63;
    const int t = blockIdx.x * 4 + wave;
    const int tg = target[t];
    const int ci = (tg >= 5000) + (tg >= 15000) + (tg >= 30000);
    const float4* h = (const float4*)(hidden + (size_t)t * D);
    const float4* w = (const float4*)(weight + (size_t)tg * D);
    const float4* c = (const float4*)(cweight + (size_t)(ci ? 3 - ci : 0) * D);
    float dw = 0.f, dc = 0.f;
    #pragma unroll
    for (int u = 0; u < 2; ++u) {
        float4 hh = h[lane * 2 + u];
        float4 ww = w[lane * 2 + u];
        float4 cc = c[lane * 2 + u];
        dw += hh.x * ww.x + hh.y * ww.y + hh.z * ww.z + hh.w * ww.w;
        dc += hh.x * cc.x + hh.y * cc.y + hh.z * cc.z + hh.w * cc.w;
    }
    #pragma unroll
    for (int off = 1; off < 64; off <<= 1) {
        dw += __shfl_xor(dw, off, 64);
        dc += __shfl_xor(dc, off, 64);
    }
    if (lane == 0) {
        float head = ci ? dc + cbias[3 - ci] : dw + bias[tg];
        float tail = ci ? dw + bias[tg]      : 0.f;
        stash[t] = make_float2(head, tail);
    }
}

// ---------------- persistent fp8 GEMM: 128x128, BK=64, cross-item prefetch ----------------
__global__ __launch_bounds__(256, 4) void k_gemm_all(
    const unsigned char* __restrict__ wsW, const float* __restrict__ wsB,
    const unsigned char* __restrict__ wsH, const unsigned char* __restrict__ wsHc,
    float2* __restrict__ headP, float2* __restrict__ tailP,
    const int* __restrict__ meta)
{
    const int nt1 = meta[6], nt2 = meta[7], nt3 = meta[8];
    const int base1 = meta[3], base2 = meta[4], base3 = meta[5];
    const int b1 = HEAD_CHUNKS * 32;
    const int b2 = b1 + 79 * nt1;
    const int b3 = b2 + 118 * nt2;
    const int b4 = b3 + 159 * nt3;

    const int tid = threadIdx.x;
    const int w = tid >> 6, lane = tid & 63;
    const int wm = w >> 1, wn = w & 1;
    const int lm = lane & 15, kg = lane >> 4;
    const int xorv = (lane & 3) << 4;          // byte XOR for swizzled read (16B granules)
    const int rowA = wm * 64 + lm;
    const int rowB = wn * 64 + lm;

    __shared__ unsigned char ldsA[2][8192];    // 128 rows x 64 B (fp8, BK=64)
    __shared__ unsigned char ldsB[2][8192];
    __shared__ float2 sred[2][128];

    auto decode = [&](int it, const unsigned char*& Wb, const unsigned char*& Hb,
                      int& p, int& chunk, int& tau, int& tokBase, int& rowBase) {
        if (it < b1)      { p = 0; chunk = it >> 5;          tau = it & 31;                 tokBase = 0; }
        else if (it < b2) { p = 1; int x = it - b1; chunk = x / nt1; tau = x - chunk * nt1; tokBase = base1; }
        else if (it < b3) { p = 2; int x = it - b2; chunk = x / nt2; tau = x - chunk * nt2; tokBase = base2; }
        else              { p = 3; int x = it - b3; chunk = x / nt3; tau = x - chunk * nt3; tokBase = base3; }
        const int pstart_[4] = {0, 5120, 15232, 30336};
        rowBase = pstart_[p] + chunk * 128;
        Wb = wsW + (size_t)rowBase * D;
        Hb = (p == 0 ? wsH + (size_t)(tau * 128) * D
                     : wsHc + (size_t)(tokBase + tau * 128) * D);
    };

    auto STAGE = [&](const unsigned char* Wb, const unsigned char* Hb, int buf, int kt) {
        #pragma unroll
        for (int j = 0; j < 2; ++j) {
            int e = j * 256 + tid;              // 16-B unit, 0..511
            int r = e >> 2;                     // row 0..127
            int q = (e & 3) ^ (r & 3);          // inverse-swizzled source quarter
            size_t go = (size_t)r * D + (size_t)kt * 64 + q * 16;
            gload_lds16(Wb + go, &ldsA[buf][e * 16]);
            gload_lds16(Hb + go, &ldsB[buf][e * 16]);
        }
    };

    int item = blockIdx.x;
    if (item >= b4) return;

    const unsigned char *Wb, *Hb;
    int p, chunk, tau, tokBase, rowBase;
    decode(item, Wb, Hb, p, chunk, tau, tokBase, rowBase);
    STAGE(Wb, Hb, 0, 0);

    while (true) {
        const int nitem = item + GRID_PERSIST;
        const bool hasNext = nitem < b4;
        const unsigned char *nWb = nullptr, *nHb = nullptr;
        int np, nchunk, ntau, ntokBase, nrowBase;
        if (hasNext) decode(nitem, nWb, nHb, np, nchunk, ntau, ntokBase, nrowBase);

        f32x4 acc[4][4];
        #pragma unroll
        for (int m = 0; m < 4; ++m)
            #pragma unroll
            for (int n = 0; n < 4; ++n) acc[m][n] = (f32x4){0.f, 0.f, 0.f, 0.f};

        __syncthreads();                        // buf0 staged & drained; sred reusable

        for (int t = 0; t < 8; ++t) {
            const int buf = t & 1;
            if (t < 7) STAGE(Wb, Hb, buf ^ 1, t + 1);
            else if (hasNext) STAGE(nWb, nHb, 0, 0);   // prefetch next item tile 0
            const char* bA = (const char*)&ldsA[buf][0];
            const char* bB = (const char*)&ldsB[buf][0];
            #pragma unroll
            for (int ks = 0; ks < 2; ++ks) {
                const int koff = (ks * 32 + kg * 8) ^ xorv;
                long af[4], bf8[4];
                #pragma unroll
                for (int m = 0; m < 4; ++m)
                    af[m] = *(const long*)(bA + (rowA + m * 16) * 64 + koff);
                #pragma unroll
                for (int n = 0; n < 4; ++n)
                    bf8[n] = *(const long*)(bB + (rowB + n * 16) * 64 + koff);
                #pragma unroll
                for (int m = 0; m < 4; ++m)
                    #pragma unroll
                    for (int n = 0; n < 4; ++n)
                        acc[m][n] = __builtin_amdgcn_mfma_f32_16x16x32_fp8_fp8(
                            af[m], bf8[n], acc[m][n], 0, 0, 0);
            }
            if (t < 7) __syncthreads();         // t=7 drains at epilogue barrier
        }

        // ---- epilogue: bias + per-token LSE over this chunk's 128 rows ----
        f32x4 bb[4];
        #pragma unroll
        for (int m = 0; m < 4; ++m)
            bb[m] = *(const f32x4*)(wsB + rowBase + wm * 64 + m * 16 + kg * 4);

        #pragma unroll
        for (int n = 0; n < 4; ++n) {
            float mval = -1e30f;
            #pragma unroll
            for (int m = 0; m < 4; ++m)
                #pragma unroll
                for (int j = 0; j < 4; ++j) {
                    acc[m][n][j] += bb[m][j];
                    mval = fmaxf(mval, acc[m][n][j]);
                }
            float sval = 0.f;
            #pragma unroll
            for (int m = 0; m < 4; ++m)
                #pragma unroll
                for (int j = 0; j < 4; ++j)
                    sval += __expf(acc[m][n][j] - mval);
            #pragma unroll
            for (int off = 16; off < 64; off <<= 1) {
                float m2 = __shfl_xor(mval, off, 64);
                float s2 = __shfl_xor(sval, off, 64);
                float M = fmaxf(mval, m2);
                sval = sval * __expf(mval - M) + s2 * __expf(m2 - M);
                mval = M;
            }
            if (lane < 16)
                sred[wm][wn * 64 + n * 16 + lane] = make_float2(mval, sval);
        }
        __syncthreads();                        // also drains t=7 reads + prefetch
        if (tid < 128) {
            float2 p0 = sred[0][tid], p1 = sred[1][tid];
            float M = fmaxf(p0.x, p1.x);
            float S = p0.y * __expf(p0.x - M) + p1.y * __expf(p1.x - M);
            if (p == 0)
                headP[(size_t)(tau * 128 + tid) * HEAD_CHUNKS + chunk] = make_float2(M, S);
            else
                tailP[(size_t)(tokBase + tau * 128 + tid) * TAILP_STRIDE + chunk] = make_float2(M, S);
        }

        if (!hasNext) break;
        item = nitem;
        Wb = nWb; Hb = nHb;
        p = np; chunk = nchunk; tau = ntau; tokBase = ntokBase; rowBase = nrowBase;
    }
}

// ---------------- merge partials -> nll ----------------
__global__ __launch_bounds__(256) void k_stageB(
    const float2* __restrict__ headP, const float2* __restrict__ tailP,
    const float2* __restrict__ stash, const int* __restrict__ target,
    const int* __restrict__ inv, float* __restrict__ out)
{
    const int wave = threadIdx.x >> 6, lane = threadIdx.x & 63;
    const int t = blockIdx.x * 4 + wave;
    const int tg = target[t];
    const int ci = (tg >= 5000) + (tg >= 15000) + (tg >= 30000);

    float m = -1e30f, s = 0.f;
    if (lane < HEAD_CHUNKS) { float2 p = headP[(size_t)t * HEAD_CHUNKS + lane]; m = p.x; s = p.y; }
    #pragma unroll
    for (int off = 1; off < 64; off <<= 1) {
        float m2 = __shfl_xor(m, off, 64);
        float s2 = __shfl_xor(s, off, 64);
        float M = fmaxf(m, m2);
        s = s * __expf(m - M) + s2 * __expf(m2 - M);
        m = M;
    }
    float2 st = stash[t];
    float nll = (m + __logf(s)) - st.x;

    if (ci) {
        const int nch_[4] = {0, 79, 118, 159};
        const int nch = nch_[ci];
        const int pos = inv[t];
        float m2 = -1e30f, s2 = 0.f;
        for (int c = lane; c < nch; c += 64) {
            float2 p = tailP[(size_t)pos * TAILP_STRIDE + c];
            float M = fmaxf(m2, p.x);
            s2 = s2 * __expf(m2 - M) + p.y * __expf(p.x - M);
            m2 = M;
        }
        #pragma unroll
        for (int off = 1; off < 64; off <<= 1) {
            float mm = __shfl_xor(m2, off, 64);
            float ss = __shfl_xor(s2, off, 64);
            float M = fmaxf(m2, mm);
            s2 = s2 * __expf(m2 - M) + ss * __expf(mm - M);
            m2 = M;
        }
        nll += (m2 + __logf(s2)) - st.y;
    }
    if (lane == 0) out[t] = nll;
}

extern "C" void kernel_launch(void* const* d_in, const int* in_sizes, int n_in,
                              void* d_out, int out_size, void* d_ws, size_t ws_size,
                              hipStream_t stream) {
    const float* hidden  = (const float*)d_in[0];
    const int*   targetp = (const int*)d_in[1];
    const float* weight  = (const float*)d_in[2];
    const float* biasp   = (const float*)d_in[3];
    const float* cweight = (const float*)d_in[4];
    const float* cbias   = (const float*)d_in[5];
    float* outp = (float*)d_out;

    char* ws = (char*)d_ws;
    unsigned char* wsW   = (unsigned char*)(ws);                   // 25,952,256 B (fp8)
    float*         wsB   = (float*)(ws + 25952256);                //    202,752 B
    unsigned char* wsH   = (unsigned char*)(ws + 26155008);        //  2,097,152 B (fp8)
    unsigned char* wsHc  = (unsigned char*)(ws + 28252160);        //  2,424,832 B (fp8)
    float2*        headP = (float2*)(ws + 30676992);               //  1,310,720 B
    float2*        tailP = (float2*)(ws + 31987712);               //  6,062,080 B
    float2*        wsS   = (float2*)(ws + 38049792);               //     32,768 B
    int*           perm  = (int*)(ws + 38082560);                  //     18,944 B
    int*           inv   = (int*)(ws + 38101504);                  //     16,384 B
    int*           meta  = (int*)(ws + 38117888);                  //         64 B

    k_bucket<<<1, 256, 0, stream>>>(targetp, perm, inv, meta);
    k_convert<<<NROWS_PAD + NTOK + NTOKP, 128, 0, stream>>>(
        weight, biasp, cweight, cbias, hidden, perm, wsW, wsB, wsH, wsHc);
    k_stash<<<NTOK / 4, 256, 0, stream>>>(hidden, targetp, weight, biasp,
                                          cweight, cbias, wsS);
    k_gemm_all<<<GRID_PERSIST, 256, 0, stream>>>(wsW, wsB, wsH, wsHc, headP, tailP, meta);
    k_stageB<<<NTOK / 4, 256, 0, stream>>>(headP, tailP, wsS, targetp, inv, outp);
}

// Round 12
// 125.951 us; speedup vs baseline: 2.9482x; 1.1427x over previous
//
#include <hip/hip_runtime.h>

// Adaptive softmax NLL — fp8(e4m3)-MFMA persistent GEMM, 4 blocks/CU,
// cross-item prefetch, period-8 LDS swizzle (2-way conflicts = free).
// Target/routing logits exact fp32 via k_stash.
//
// Packed fp8 weight in ws (128-row chunks, row = 512 B):
//   head : rows [0,5120)      = weight[0:5000] ++ cluster_weight ++ pad (40 chunks)
//   tail1: rows [5120,15232)  = weight[5000:15000]  ++ pad (79 chunks)
//   tail2: rows [15232,30336) = weight[15000:30000] ++ pad (118 chunks)
//   tail3: rows [30336,50688) = weight[30000:50257] ++ pad (159 chunks)
// Pad rows: w=0, bias=-1e30 (vanish in exp-weighted LSE merges).
// Work item = (partition, chunk, token-tile), exact list, persistent CTAs.

#define D 512
#define NROWS_PAD 50688
#define NTOK 4096
#define NTOKP 4736
#define HEAD_CHUNKS 40
#define TAILP_STRIDE 160
#define GRID_PERSIST 1024

typedef __attribute__((ext_vector_type(4))) float f32x4;

__device__ __forceinline__ unsigned f2fp8(float f) {
    // f32 -> OCP e4m3fn, RNE, saturate to 448
    unsigned u = __float_as_uint(f);
    unsigned s = (u >> 24) & 0x80u;
    unsigned a = u & 0x7FFFFFFFu;
    if (a >= 0x43E00000u) return s | 0x7Eu;          // >= 448 -> sat
    if (a < 0x3C800000u) {                            // < 2^-6 -> subnormal
        int n = __float2int_rn(__uint_as_float(a) * 512.f);
        return s | (unsigned)n;
    }
    unsigned lsb = (a >> 20) & 1u;
    a += 0x7FFFFu + lsb;                              // RNE at bit 20
    unsigned e = (a >> 23) - 120u;
    unsigned m = (a >> 20) & 7u;
    if (e >= 16u || (e == 15u && m == 7u)) return s | 0x7Eu;
    return s | (e << 3) | m;
}

__device__ __forceinline__ void gload_lds16(const void* g, void* l) {
    __builtin_amdgcn_global_load_lds(
        (const __attribute__((address_space(1))) unsigned int*)g,
        (__attribute__((address_space(3))) unsigned int*)l, 16, 0, 0);
}

// ---------------- bucket tokens by cluster (deterministic counting sort) ----------------
__global__ __launch_bounds__(256) void k_bucket(
    const int* __restrict__ target, int* __restrict__ perm,
    int* __restrict__ inv, int* __restrict__ meta)
{
    __shared__ int cnt[256][4];
    __shared__ int basesh[256][4];
    __shared__ int sTot[4], sOff[4];
    const int th = threadIdx.x;
    for (int p = th; p < NTOKP; p += 256) perm[p] = -1;
    int lc[4] = {0, 0, 0, 0};
    #pragma unroll
    for (int i = 0; i < 16; ++i) {
        int tg = target[th * 16 + i];
        int c = (tg >= 5000) + (tg >= 15000) + (tg >= 30000);
        lc[c]++;
    }
    #pragma unroll
    for (int c = 0; c < 4; ++c) cnt[th][c] = lc[c];
    __syncthreads();
    if (th < 4) {
        int tot = 0;
        for (int i = 0; i < 256; ++i) tot += cnt[i][th];
        sTot[th] = tot;
    }
    __syncthreads();
    if (th == 0) {
        int b = 0;
        for (int c = 1; c < 4; ++c) { sOff[c] = b; b += ((sTot[c] + 127) >> 7) << 7; }
        meta[0] = sTot[1]; meta[1] = sTot[2]; meta[2] = sTot[3];
        meta[3] = sOff[1]; meta[4] = sOff[2]; meta[5] = sOff[3];
        meta[6] = (sTot[1] + 127) >> 7;
        meta[7] = (sTot[2] + 127) >> 7;
        meta[8] = (sTot[3] + 127) >> 7;
    }
    __syncthreads();
    if (th >= 1 && th < 4) {
        int run = sOff[th];
        for (int i = 0; i < 256; ++i) { basesh[i][th] = run; run += cnt[i][th]; }
    }
    __syncthreads();
    int run[4];
    #pragma unroll
    for (int c = 1; c < 4; ++c) run[c] = basesh[th][c];
    for (int i = 0; i < 16; ++i) {
        int t = th * 16 + i;
        int tg = target[t];
        int c = (tg >= 5000) + (tg >= 15000) + (tg >= 30000);
        if (c > 0) { int pos = run[c]++; perm[pos] = t; inv[t] = pos; }
        else inv[t] = -1;
    }
}

// ---------------- convert to fp8 / reorder / pad / gather ----------------
__global__ __launch_bounds__(128) void k_convert(
    const float* __restrict__ weight, const float* __restrict__ bias,
    const float* __restrict__ cweight, const float* __restrict__ cbias,
    const float* __restrict__ hidden, const int* __restrict__ perm,
    unsigned char* __restrict__ wsW, float* __restrict__ wsB,
    unsigned char* __restrict__ wsH, unsigned char* __restrict__ wsHc)
{
    const int r = blockIdx.x;
    const int i = threadIdx.x;   // 0..127, one float4 -> 4 fp8 bytes each
    float4 v = make_float4(0.f, 0.f, 0.f, 0.f);
    unsigned* dst;
    if (r < NROWS_PAD) {
        const int pstart[4] = {0, 5120, 15232, 30336};
        const int plen[4]   = {5003, 10000, 15000, 20257};
        const int psrc[4]   = {0, 5000, 15000, 30000};
        int p = (r < 5120) ? 0 : (r < 15232) ? 1 : (r < 30336) ? 2 : 3;
        int o = r - pstart[p];
        const float* src = nullptr;
        float b = -1e30f;
        if (o < plen[p]) {
            if (p == 0 && o >= 5000) { src = cweight + (size_t)(o - 5000) * D; b = cbias[o - 5000]; }
            else { int sr = psrc[p] + o; src = weight + (size_t)sr * D; b = bias[sr]; }
        }
        if (src) v = ((const float4*)src)[i];
        if (i == 0) wsB[r] = b;
        dst = (unsigned*)(wsW + (size_t)r * D);
    } else if (r < NROWS_PAD + NTOK) {
        int hr = r - NROWS_PAD;
        v = ((const float4*)(hidden + (size_t)hr * D))[i];
        dst = (unsigned*)(wsH + (size_t)hr * D);
    } else {
        int p = r - NROWS_PAD - NTOK;       // compacted position
        int tok = perm[p];
        if (tok >= 0) v = ((const float4*)(hidden + (size_t)tok * D))[i];
        dst = (unsigned*)(wsHc + (size_t)p * D);
    }
    unsigned pk = f2fp8(v.x) | (f2fp8(v.y) << 8) | (f2fp8(v.z) << 16) | (f2fp8(v.w) << 24);
    dst[i] = pk;
}

// ---------------- exact fp32 dots for the two needed logits ----------------
__global__ __launch_bounds__(256) void k_stash(
    const float* __restrict__ hidden, const int* __restrict__ target,
    const float* __restrict__ weight, const float* __restrict__ bias,
    const float* __restrict__ cweight, const float* __restrict__ cbias,
    float2* __restrict__ stash)
{
    const int wave = threadIdx.x >> 6, lane = threadIdx.x & 63;
    const int t = blockIdx.x * 4 + wave;
    const int tg = target[t];
    const int ci = (tg >= 5000) + (tg >= 15000) + (tg >= 30000);
    const float4* h = (const float4*)(hidden + (size_t)t * D);
    const float4* w = (const float4*)(weight + (size_t)tg * D);
    const float4* c = (const float4*)(cweight + (size_t)(ci ? 3 - ci : 0) * D);
    float dw = 0.f, dc = 0.f;
    #pragma unroll
    for (int u = 0; u < 2; ++u) {
        float4 hh = h[lane * 2 + u];
        float4 ww = w[lane * 2 + u];
        float4 cc = c[lane * 2 + u];
        dw += hh.x * ww.x + hh.y * ww.y + hh.z * ww.z + hh.w * ww.w;
        dc += hh.x * cc.x + hh.y * cc.y + hh.z * cc.z + hh.w * cc.w;
    }
    #pragma unroll
    for (int off = 1; off < 64; off <<= 1) {
        dw += __shfl_xor(dw, off, 64);
        dc += __shfl_xor(dc, off, 64);
    }
    if (lane == 0) {
        float head = ci ? dc + cbias[3 - ci] : dw + bias[tg];
        float tail = ci ? dw + bias[tg]      : 0.f;
        stash[t] = make_float2(head, tail);
    }
}

// ---------------- persistent fp8 GEMM: 128x128, BK=64, cross-item prefetch ----------------
// LDS swizzle: granule (row r, quarter q) stored at LDS quarter q ^ ((r>>1)&3).
// Bank(row, q) = 16*(r&1) + 4*(q ^ ((r>>1)&3)) -> injective over r mod 8:
// 16 lanes spread across 8 bank-pairs = 2-way conflict = free (m136).
__global__ __launch_bounds__(256, 4) void k_gemm_all(
    const unsigned char* __restrict__ wsW, const float* __restrict__ wsB,
    const unsigned char* __restrict__ wsH, const unsigned char* __restrict__ wsHc,
    float2* __restrict__ headP, float2* __restrict__ tailP,
    const int* __restrict__ meta)
{
    const int nt1 = meta[6], nt2 = meta[7], nt3 = meta[8];
    const int base1 = meta[3], base2 = meta[4], base3 = meta[5];
    const int b1 = HEAD_CHUNKS * 32;
    const int b2 = b1 + 79 * nt1;
    const int b3 = b2 + 118 * nt2;
    const int b4 = b3 + 159 * nt3;

    const int tid = threadIdx.x;
    const int w = tid >> 6, lane = tid & 63;
    const int wm = w >> 1, wn = w & 1;
    const int lm = lane & 15, kg = lane >> 4;
    const int xorv = ((lane >> 1) & 3) << 4;   // read XOR: quarter ^ ((row>>1)&3), row≡lm mod 8
    const int rowA = wm * 64 + lm;
    const int rowB = wn * 64 + lm;

    __shared__ unsigned char ldsA[2][8192];    // 128 rows x 64 B (fp8, BK=64)
    __shared__ unsigned char ldsB[2][8192];
    __shared__ float2 sred[2][128];

    auto decode = [&](int it, const unsigned char*& Wb, const unsigned char*& Hb,
                      int& p, int& chunk, int& tau, int& tokBase, int& rowBase) {
        if (it < b1)      { p = 0; chunk = it >> 5;          tau = it & 31;                 tokBase = 0; }
        else if (it < b2) { p = 1; int x = it - b1; chunk = x / nt1; tau = x - chunk * nt1; tokBase = base1; }
        else if (it < b3) { p = 2; int x = it - b2; chunk = x / nt2; tau = x - chunk * nt2; tokBase = base2; }
        else              { p = 3; int x = it - b3; chunk = x / nt3; tau = x - chunk * nt3; tokBase = base3; }
        const int pstart_[4] = {0, 5120, 15232, 30336};
        rowBase = pstart_[p] + chunk * 128;
        Wb = wsW + (size_t)rowBase * D;
        Hb = (p == 0 ? wsH + (size_t)(tau * 128) * D
                     : wsHc + (size_t)(tokBase + tau * 128) * D);
    };

    auto STAGE = [&](const unsigned char* Wb, const unsigned char* Hb, int buf, int kt) {
        #pragma unroll
        for (int j = 0; j < 2; ++j) {
            int e = j * 256 + tid;              // 16-B unit, 0..511
            int r = e >> 2;                     // row 0..127
            int q = (e & 3) ^ ((r >> 1) & 3);   // inverse-swizzled source quarter
            size_t go = (size_t)r * D + (size_t)kt * 64 + q * 16;
            gload_lds16(Wb + go, &ldsA[buf][e * 16]);
            gload_lds16(Hb + go, &ldsB[buf][e * 16]);
        }
    };

    int item = blockIdx.x;
    if (item >= b4) return;

    const unsigned char *Wb, *Hb;
    int p, chunk, tau, tokBase, rowBase;
    decode(item, Wb, Hb, p, chunk, tau, tokBase, rowBase);
    STAGE(Wb, Hb, 0, 0);

    while (true) {
        const int nitem = item + GRID_PERSIST;
        const bool hasNext = nitem < b4;
        const unsigned char *nWb = nullptr, *nHb = nullptr;
        int np, nchunk, ntau, ntokBase, nrowBase;
        if (hasNext) decode(nitem, nWb, nHb, np, nchunk, ntau, ntokBase, nrowBase);

        f32x4 acc[4][4];
        #pragma unroll
        for (int m = 0; m < 4; ++m)
            #pragma unroll
            for (int n = 0; n < 4; ++n) acc[m][n] = (f32x4){0.f, 0.f, 0.f, 0.f};

        __syncthreads();                        // buf0 staged & drained; sred reusable

        for (int t = 0; t < 8; ++t) {
            const int buf = t & 1;
            if (t < 7) STAGE(Wb, Hb, buf ^ 1, t + 1);
            else if (hasNext) STAGE(nWb, nHb, 0, 0);   // prefetch next item tile 0
            const char* bA = (const char*)&ldsA[buf][0];
            const char* bB = (const char*)&ldsB[buf][0];
            #pragma unroll
            for (int ks = 0; ks < 2; ++ks) {
                const int koff = (ks * 32 + kg * 8) ^ xorv;
                long af[4], bf8[4];
                #pragma unroll
                for (int m = 0; m < 4; ++m)
                    af[m] = *(const long*)(bA + (rowA + m * 16) * 64 + koff);
                #pragma unroll
                for (int n = 0; n < 4; ++n)
                    bf8[n] = *(const long*)(bB + (rowB + n * 16) * 64 + koff);
                #pragma unroll
                for (int m = 0; m < 4; ++m)
                    #pragma unroll
                    for (int n = 0; n < 4; ++n)
                        acc[m][n] = __builtin_amdgcn_mfma_f32_16x16x32_fp8_fp8(
                            af[m], bf8[n], acc[m][n], 0, 0, 0);
            }
            if (t < 7) __syncthreads();         // t=7 drains at epilogue barrier
        }

        // ---- epilogue: bias + per-token LSE over this chunk's 128 rows ----
        f32x4 bb[4];
        #pragma unroll
        for (int m = 0; m < 4; ++m)
            bb[m] = *(const f32x4*)(wsB + rowBase + wm * 64 + m * 16 + kg * 4);

        #pragma unroll
        for (int n = 0; n < 4; ++n) {
            float mval = -1e30f;
            #pragma unroll
            for (int m = 0; m < 4; ++m)
                #pragma unroll
                for (int j = 0; j < 4; ++j) {
                    acc[m][n][j] += bb[m][j];
                    mval = fmaxf(mval, acc[m][n][j]);
                }
            float sval = 0.f;
            #pragma unroll
            for (int m = 0; m < 4; ++m)
                #pragma unroll
                for (int j = 0; j < 4; ++j)
                    sval += __expf(acc[m][n][j] - mval);
            #pragma unroll
            for (int off = 16; off < 64; off <<= 1) {
                float m2 = __shfl_xor(mval, off, 64);
                float s2 = __shfl_xor(sval, off, 64);
                float M = fmaxf(mval, m2);
                sval = sval * __expf(mval - M) + s2 * __expf(m2 - M);
                mval = M;
            }
            if (lane < 16)
                sred[wm][wn * 64 + n * 16 + lane] = make_float2(mval, sval);
        }
        __syncthreads();                        // also drains t=7 reads + prefetch
        if (tid < 128) {
            float2 p0 = sred[0][tid], p1 = sred[1][tid];
            float M = fmaxf(p0.x, p1.x);
            float S = p0.y * __expf(p0.x - M) + p1.y * __expf(p1.x - M);
            if (p == 0)
                headP[(size_t)(tau * 128 + tid) * HEAD_CHUNKS + chunk] = make_float2(M, S);
            else
                tailP[(size_t)(tokBase + tau * 128 + tid) * TAILP_STRIDE + chunk] = make_float2(M, S);
        }

        if (!hasNext) break;
        item = nitem;
        Wb = nWb; Hb = nHb;
        p = np; chunk = nchunk; tau = ntau; tokBase = ntokBase; rowBase = nrowBase;
    }
}

// ---------------- merge partials -> nll ----------------
__global__ __launch_bounds__(256) void k_stageB(
    const float2* __restrict__ headP, const float2* __restrict__ tailP,
    const float2* __restrict__ stash, const int* __restrict__ target,
    const int* __restrict__ inv, float* __restrict__ out)
{
    const int wave = threadIdx.x >> 6, lane = threadIdx.x & 63;
    const int t = blockIdx.x * 4 + wave;
    const int tg = target[t];
    const int ci = (tg >= 5000) + (tg >= 15000) + (tg >= 30000);

    float m = -1e30f, s = 0.f;
    if (lane < HEAD_CHUNKS) { float2 p = headP[(size_t)t * HEAD_CHUNKS + lane]; m = p.x; s = p.y; }
    #pragma unroll
    for (int off = 1; off < 64; off <<= 1) {
        float m2 = __shfl_xor(m, off, 64);
        float s2 = __shfl_xor(s, off, 64);
        float M = fmaxf(m, m2);
        s = s * __expf(m - M) + s2 * __expf(m2 - M);
        m = M;
    }
    float2 st = stash[t];
    float nll = (m + __logf(s)) - st.x;

    if (ci) {
        const int nch_[4] = {0, 79, 118, 159};
        const int nch = nch_[ci];
        const int pos = inv[t];
        float m2 = -1e30f, s2 = 0.f;
        for (int c = lane; c < nch; c += 64) {
            float2 p = tailP[(size_t)pos * TAILP_STRIDE + c];
            float M = fmaxf(m2, p.x);
            s2 = s2 * __expf(m2 - M) + p.y * __expf(p.x - M);
            m2 = M;
        }
        #pragma unroll
        for (int off = 1; off < 64; off <<= 1) {
            float mm = __shfl_xor(m2, off, 64);
            float ss = __shfl_xor(s2, off, 64);
            float M = fmaxf(m2, mm);
            s2 = s2 * __expf(m2 - M) + ss * __expf(mm - M);
            m2 = M;
        }
        nll += (m2 + __logf(s2)) - st.y;
    }
    if (lane == 0) out[t] = nll;
}

extern "C" void kernel_launch(void* const* d_in, const int* in_sizes, int n_in,
                              void* d_out, int out_size, void* d_ws, size_t ws_size,
                              hipStream_t stream) {
    const float* hidden  = (const float*)d_in[0];
    const int*   targetp = (const int*)d_in[1];
    const float* weight  = (const float*)d_in[2];
    const float* biasp   = (const float*)d_in[3];
    const float* cweight = (const float*)d_in[4];
    const float* cbias   = (const float*)d_in[5];
    float* outp = (float*)d_out;

    char* ws = (char*)d_ws;
    unsigned char* wsW   = (unsigned char*)(ws);                   // 25,952,256 B (fp8)
    float*         wsB   = (float*)(ws + 25952256);                //    202,752 B
    unsigned char* wsH   = (unsigned char*)(ws + 26155008);        //  2,097,152 B (fp8)
    unsigned char* wsHc  = (unsigned char*)(ws + 28252160);        //  2,424,832 B (fp8)
    float2*        headP = (float2*)(ws + 30676992);               //  1,310,720 B
    float2*        tailP = (float2*)(ws + 31987712);               //  6,062,080 B
    float2*        wsS   = (float2*)(ws + 38049792);               //     32,768 B
    int*           perm  = (int*)(ws + 38082560);                  //     18,944 B
    int*           inv   = (int*)(ws + 38101504);                  //     16,384 B
    int*           meta  = (int*)(ws + 38117888);                  //         64 B

    k_bucket<<<1, 256, 0, stream>>>(targetp, perm, inv, meta);
    k_convert<<<NROWS_PAD + NTOK + NTOKP, 128, 0, stream>>>(
        weight, biasp, cweight, cbias, hidden, perm, wsW, wsB, wsH, wsHc);
    k_stash<<<NTOK / 4, 256, 0, stream>>>(hidden, targetp, weight, biasp,
                                          cweight, cbias, wsS);
    k_gemm_all<<<GRID_PERSIST, 256, 0, stream>>>(wsW, wsB, wsH, wsHc, headP, tailP, meta);
    k_stageB<<<NTOK / 4, 256, 0, stream>>>(headP, tailP, wsS, targetp, inv, outp);
}